// Round 6
// baseline (470.448 us; speedup 1.0000x reference)
//
#include <hip/hip_runtime.h>
#include <hip/hip_bf16.h>
#include <math.h>

typedef __bf16 bf16;
typedef __attribute__((ext_vector_type(8))) __bf16 bf16x8;
typedef __attribute__((ext_vector_type(4))) __bf16 bf16x4;
typedef __attribute__((ext_vector_type(4))) float f32x4;
typedef __attribute__((ext_vector_type(4))) unsigned int u32x4;

constexpr int NB = 2, NH = 16, SQ = 2048, SKV = 2048, DH = 128;
constexpr int QB = 64, KVB = 32;
constexpr float SM_SCALE = 0.08838834764831845f;  // 1/sqrt(128)
constexpr float LOG2E = 1.4426950408889634f;
constexpr float DEFER_THR = 7.0f;                 // T13: p bounded by e^7

#define GLD_LDS(g, l) __builtin_amdgcn_global_load_lds( \
    (const __attribute__((address_space(1))) void*)(g), \
    (__attribute__((address_space(3))) void*)(l), 16, 0, 0)

__device__ __forceinline__ unsigned cvt_pk_bf16(float lo, float hi) {
    unsigned r;
    asm("v_cvt_pk_bf16_f32 %0, %1, %2" : "=v"(r) : "v"(lo), "v"(hi));
    return r;
}

// ---- pre-pass 1: K fp32 -> bf16, layout unchanged [bh][skv][d] ----
__global__ __launch_bounds__(256)
void cvt_k_kernel(const float* __restrict__ src, bf16* __restrict__ dst) {
    const size_t i = ((size_t)blockIdx.x * 256 + threadIdx.x) * 8;
    float4 a = *(const float4*)(src + i);
    float4 b = *(const float4*)(src + i + 4);
    bf16x8 f;
    f[0]=(bf16)a.x; f[1]=(bf16)a.y; f[2]=(bf16)a.z; f[3]=(bf16)a.w;
    f[4]=(bf16)b.x; f[5]=(bf16)b.y; f[6]=(bf16)b.z; f[7]=(bf16)b.w;
    *(bf16x8*)(dst + i) = f;
}

// ---- pre-pass 2: V fp32 [bh][skv][d] -> bf16 transposed [bh][d][skv] ----
__global__ __launch_bounds__(256)
void tr_v_kernel(const float* __restrict__ src, bf16* __restrict__ dst) {
    __shared__ float Tl[64][65];
    const int bh  = blockIdx.y;
    const int kv0 = (int)(blockIdx.x >> 1) * 64;
    const int d0  = (int)(blockIdx.x & 1) * 64;
    const int t   = threadIdx.x;
    const float* sp = src + (size_t)bh * SQ * DH;
#pragma unroll
    for (int i = 0; i < 4; ++i) {
        const int row = i * 16 + (t >> 4);
        const int c4  = (t & 15) * 4;
        *(float4*)&Tl[row][c4] = *(const float4*)(sp + (size_t)(kv0 + row) * DH + d0 + c4);
    }
    __syncthreads();
    bf16* dp = dst + (size_t)bh * DH * SKV;
#pragma unroll
    for (int i = 0; i < 4; ++i) {
        const int d  = i * 16 + (t >> 4);
        const int k4 = (t & 15) * 4;
        bf16x4 o;
        o[0]=(bf16)Tl[k4+0][d]; o[1]=(bf16)Tl[k4+1][d];
        o[2]=(bf16)Tl[k4+2][d]; o[3]=(bf16)Tl[k4+3][d];
        *(bf16x4*)(dp + (size_t)(d0 + d) * SKV + kv0 + k4) = o;
    }
}

// ---- main attention kernel: 16-row waves (16x16x32 MFMA, VGPR<=64 for
//      8 waves/SIMD), QB=64, 8 waves = 4 rg x 2 kv-parities.
//      K in LDS (4-buf parity rotation, sigma-permuted rows so P is PV-B
//      lane-local); V read DIRECT from global V^T (L2-resident) as the PV
//      A-operand -> LDS = 34 KB -> 4 blocks/CU = 32 waves/CU.
//      qt map {31-r,16+r,15-r,r} per y-octet: every CU gets equal work. ----
__global__ __launch_bounds__(512, 8)
void attn_fwd_kernel(const float* __restrict__ Qg, const bf16* __restrict__ Kb,
                     const bf16* __restrict__ Vb, const float* __restrict__ Bg,
                     float* __restrict__ Og, float* __restrict__ Sg)
{
    // 0..32KB: K bufs [4][32 rows][128 d] bf16 (sigma rows + 16-slot XOR)
    // epilogue alias: 0..32KB O-merge [4rg][64 ln][32 f32]; +1KB m; +1KB l
    __shared__ __attribute__((aligned(16))) char smem[34816];
    bf16* const KlB = (bf16*)smem;
    float* const Om = (float*)smem;
    float* const Mm = (float*)(smem + 32768);
    float* const Lm = (float*)(smem + 32768 + 1024);

    const int tid = threadIdx.x;
    const int w   = tid >> 6;          // 0..7
    const int rg  = w & 3;             // row-group (16 q rows)
    const int par = w >> 2;            // kv parity
    const int ln  = tid & 63;
    const int lm  = ln & 15;           // q-col within the wave's 16 rows
    const int l4  = ln >> 4;           // k-quarter (kv slice 8*l4..8*l4+7)

    const int bh = blockIdx.x;
    const int h  = bh & (NH - 1);
    // balanced qt map: CU's y-set {r,r+8,r+16,r+24} -> qts {31-r,16+r,15-r,r},
    // per-CU tile total constant (132); heaviest first (LPT).
    const int yy = (int)blockIdx.y;
    const int r7 = yy & 7, gg = yy >> 3;
    const int qt = (gg == 0) ? 31 - r7 : (gg == 1) ? 16 + r7
                 : (gg == 2) ? 15 - r7 : r7;
    const int q0 = qt * QB;
    const int qw = q0 + rg * 16;                   // wave's first q row
    const int qr = qw + lm;                        // this lane's q row

    const float slope = exp2f(-0.5f * (float)(h + 1));
    const bf16* kbase = Kb + (size_t)bh * SKV * DH;
    const bf16* vbase = Vb + (size_t)bh * DH * SKV;
    const float* bprow = Bg + (size_t)qr * SKV;

    // K staging (both-sides rule): LDS row rl = 16b+4h'+r holds global kv
    // sigma(rl) = 8h'+4b+r; within-row slot sp holds d-slot sp^(rl&15).
    // Wave w stages rows 4w..4w+3: sigma = 8*(w&3) + 4*(w>>2) + (ln>>4).
    const int srow  = 8 * (w & 3) + 4 * (w >> 2) + l4;
    const int sslot = lm ^ ((4 * w + l4) & 15);
    const int ksrc  = srow * DH + (sslot << 3);

    auto stage = [&](int kv0n, int buf) {
        GLD_LDS(kbase + (size_t)kv0n * DH + ksrc, KlB + buf * 4096 + w * 512);
    };

    const int ntile = 2 * qt + 2;
    const int niter = qt + 1;

    stage(0, 0);
    stage(KVB, 1);

    // ---- Q fragments (pre-scaled, bf16); MFMA B operand: B[k=8*l4+j][col=lm] ----
    bf16x8 qf[4];
    {
        const float* qrow = Qg + (size_t)bh * SQ * DH + (size_t)qr * DH;
#pragma unroll
        for (int s = 0; s < 4; ++s) {
            const float* qp = qrow + s * 32 + l4 * 8;
            float4 a = *(const float4*)qp;
            float4 b = *(const float4*)(qp + 4);
            bf16x8 f;
            f[0]=(bf16)(a.x*SM_SCALE); f[1]=(bf16)(a.y*SM_SCALE);
            f[2]=(bf16)(a.z*SM_SCALE); f[3]=(bf16)(a.w*SM_SCALE);
            f[4]=(bf16)(b.x*SM_SCALE); f[5]=(bf16)(b.y*SM_SCALE);
            f[6]=(bf16)(b.z*SM_SCALE); f[7]=(bf16)(b.w*SM_SCALE);
            qf[s] = f;
        }
    }

    // O^T: acc[dt][r] = O[q=qr][d = dt*16 + 4*l4 + r]
    f32x4 acc[8];
#pragma unroll
    for (int dt = 0; dt < 8; ++dt) acc[dt] = (f32x4){0.f, 0.f, 0.f, 0.f};
    float denom = 0.f;                 // per-lane partial (own kv quarter)
    float mrow = -INFINITY;

    const int rlo = 4 * (lm >> 2) + (lm & 3);   // A-read LDS row (in 16-block) + xor key

    __syncthreads();

    for (int i = 0; i < niter; ++i) {
        const int tA = 2 * i;
        // stage tiles tA+2, tA+3 (their bufs were read in iter i-1; barrier passed)
        if (tA + 2 < ntile) stage((tA + 2) * KVB, (tA + 2) & 3);
        if (tA + 3 < ntile) stage((tA + 3) * KVB, (tA + 3) & 3);

        const int myt = tA + par;                  // this parity's tile
        const int kv0 = myt * KVB;
        const bf16* Kc = KlB + (myt & 3) * 4096;
        const bool live = (kv0 <= qw + 15);        // wave-uniform
        if (live) {
            // bias for own gamma slice: B[qr][kv0 + 8*l4 + {0..3 | 4..7}]
            const float* bp = bprow + kv0 + 8 * l4;
            f32x4 bv0 = *(const f32x4*)bp;
            f32x4 bv1 = *(const f32x4*)(bp + 4);

            // ---- S^T = K (Q*scale)^T : two 16-kv blocks, 4 d-steps of 32 ----
            f32x4 s0 = {0.f,0.f,0.f,0.f}, s1 = {0.f,0.f,0.f,0.f};
            __builtin_amdgcn_s_setprio(1);
#pragma unroll
            for (int s = 0; s < 4; ++s) {
                const int so = (((4 * s + l4) ^ rlo) << 3);
                bf16x8 k0 = *(const bf16x8*)&Kc[rlo * DH + so];
                bf16x8 k1 = *(const bf16x8*)&Kc[(16 + rlo) * DH + so];
                s0 = __builtin_amdgcn_mfma_f32_16x16x32_bf16(k0, qf[s], s0, 0, 0, 0);
                s1 = __builtin_amdgcn_mfma_f32_16x16x32_bf16(k1, qf[s], s1, 0, 0, 0);
            }
            __builtin_amdgcn_s_setprio(0);

            // lane owns P for q=qr, kv-in-tile gamma = 8*l4 + 4*b + r
            const int dq = qr - kv0;
            const float basef = slope * (float)(kv0 - qr);
            float p0[4], p1[4];
            const bool needMask = (kv0 + KVB - 1 > qw);
            if (needMask) {
#pragma unroll
                for (int r = 0; r < 4; ++r) {
                    const int g0 = 8 * l4 + r;
                    const int g1 = g0 + 4;
                    float x0 = s0[r] + bv0[r] + fmaf(slope, (float)g0, basef);
                    float x1 = s1[r] + bv1[r] + fmaf(slope, (float)g1, basef);
                    p0[r] = (g0 > dq) ? -INFINITY : x0;
                    p1[r] = (g1 > dq) ? -INFINITY : x1;
                }
            } else {
#pragma unroll
                for (int r = 0; r < 4; ++r) {
                    const int g0 = 8 * l4 + r;
                    p0[r] = s0[r] + bv0[r] + fmaf(slope, (float)g0, basef);
                    p1[r] = s1[r] + bv1[r] + fmaf(slope, (float)(g0 + 4), basef);
                }
            }

            // row max: in-lane tree (8) + co-owner butterfly (xor 16, 32)
            float mx = fmaxf(fmaxf(fmaxf(p0[0], p0[1]), fmaxf(p0[2], p0[3])),
                             fmaxf(fmaxf(p1[0], p1[1]), fmaxf(p1[2], p1[3])));
            mx = fmaxf(mx, __shfl_xor(mx, 16));
            mx = fmaxf(mx, __shfl_xor(mx, 32));

            // T13 defer-max
            if (__any(mx > mrow + DEFER_THR)) {
                const float mn = fmaxf(mrow, mx);
                const float al = exp2f((mrow - mn) * LOG2E);
                mrow = mn;
#pragma unroll
                for (int dt = 0; dt < 8; ++dt) {
                    f32x4 a = acc[dt];
                    a[0] *= al; a[1] *= al; a[2] *= al; a[3] *= al;
                    acc[dt] = a;
                }
                denom *= al;
            }

#pragma unroll
            for (int r = 0; r < 4; ++r) {
                p0[r] = exp2f((p0[r] - mrow) * LOG2E);
                p1[r] = exp2f((p1[r] - mrow) * LOG2E);
            }
            denom += ((p0[0] + p0[1]) + (p0[2] + p0[3])) +
                     ((p1[0] + p1[1]) + (p1[2] + p1[3]));

            // ---- PV: O^T += V^T P^T. pb lane-local (sigma made gamma = B k-slot);
            // V^T A-operand read DIRECT from global (L2-resident). ----
            unsigned u0 = cvt_pk_bf16(p0[0], p0[1]);
            unsigned u1 = cvt_pk_bf16(p0[2], p0[3]);
            unsigned u2 = cvt_pk_bf16(p1[0], p1[1]);
            unsigned u3 = cvt_pk_bf16(p1[2], p1[3]);
            u32x4 pw; pw[0] = u0; pw[1] = u1; pw[2] = u2; pw[3] = u3;
            const bf16x8 pb = __builtin_bit_cast(bf16x8, pw);

            const bf16* vp = vbase + (size_t)lm * SKV + kv0 + 8 * l4;
            __builtin_amdgcn_s_setprio(1);
#pragma unroll
            for (int dt = 0; dt < 8; ++dt) {
                bf16x8 vb = *(const bf16x8*)(vp + (size_t)dt * (16 * SKV));
                acc[dt] = __builtin_amdgcn_mfma_f32_16x16x32_bf16(vb, pb, acc[dt], 0, 0, 0);
            }
            __builtin_amdgcn_s_setprio(0);
        }

        __syncthreads();  // staging drain + 2-tile buffer handoff
    }

    // ---- epilogue: parity merge via LDS (aliases K bufs; drained), store ----
    const int sl = rg * 64 + ln;
    if (par == 1) {
        Mm[sl] = mrow;
        Lm[sl] = denom;
#pragma unroll
        for (int dt = 0; dt < 8; ++dt)
            *(f32x4*)&Om[sl * 32 + ((dt ^ (ln & 7)) << 2)] = acc[dt];
    }
    __syncthreads();
    if (par == 0) {
        const float m1 = Mm[sl];
        const float l1 = Lm[sl];
        const float m  = fmaxf(mrow, m1);
        const float a0 = exp2f((mrow - m) * LOG2E);
        const float a1 = exp2f((m1 - m) * LOG2E);
        float dme = a0 * denom + a1 * l1;
        dme += __shfl_xor(dme, 16);
        dme += __shfl_xor(dme, 32);
        const float inv = 1.0f / dme;
        float* orow = Og + (size_t)bh * SQ * DH + (size_t)qr * DH;
#pragma unroll
        for (int dt = 0; dt < 8; ++dt) {
            f32x4 o1 = *(const f32x4*)&Om[sl * 32 + ((dt ^ (ln & 7)) << 2)];
            f32x4 o;
            o[0] = (a0 * acc[dt][0] + a1 * o1[0]) * inv;
            o[1] = (a0 * acc[dt][1] + a1 * o1[1]) * inv;
            o[2] = (a0 * acc[dt][2] + a1 * o1[2]) * inv;
            o[3] = (a0 * acc[dt][3] + a1 * o1[3]) * inv;
            *(f32x4*)(orow + dt * 16 + l4 * 4) = o;
        }
        if (l4 == 0)
            Sg[(size_t)bh * SQ + qr] = m + logf(dme);
    }
}

extern "C" void kernel_launch(void* const* d_in, const int* in_sizes, int n_in,
                              void* d_out, int out_size, void* d_ws, size_t ws_size,
                              hipStream_t stream) {
    const float* Q = (const float*)d_in[0];
    const float* K = (const float*)d_in[1];
    const float* V = (const float*)d_in[2];
    const float* B = (const float*)d_in[3];
    float* O     = (float*)d_out;
    float* Stats = O + (size_t)NB * NH * SQ * DH;

    const size_t nkv = (size_t)NB * NH * SKV * DH;
    bf16* Kb = (bf16*)d_ws;
    bf16* Vt = Kb + nkv;

    cvt_k_kernel<<<(int)(nkv / (256 * 8)), 256, 0, stream>>>(K, Kb);
    tr_v_kernel<<<dim3(64, NB * NH), 256, 0, stream>>>(V, Vt);

    dim3 grid(NB * NH, SQ / QB);   // (32 bh, 32 q-tiles), balanced qt map in-kernel
    attn_fwd_kernel<<<grid, 512, 0, stream>>>(Q, Kb, Vt, B, O, Stats);
}

// Round 8
// 439.606 us; speedup vs baseline: 1.0702x; 1.0702x over previous
//
#include <hip/hip_runtime.h>
#include <hip/hip_bf16.h>
#include <math.h>

typedef __bf16 bf16;
typedef __attribute__((ext_vector_type(8))) __bf16 bf16x8;
typedef __attribute__((ext_vector_type(4))) __bf16 bf16x4;
typedef __attribute__((ext_vector_type(4))) float f32x4;

constexpr int NB = 2, NH = 16, SQ = 2048, SKV = 2048, DH = 128;
constexpr int QB = 128, KVB = 64;
constexpr float SM_SCALE = 0.08838834764831845f;  // 1/sqrt(128)
constexpr float LOG2E = 1.4426950408889634f;
constexpr float DEFER_THR = 7.0f;                 // T13: p bounded by e^7

#define GLD_LDS(g, l) __builtin_amdgcn_global_load_lds( \
    (const __attribute__((address_space(1))) void*)(g), \
    (__attribute__((address_space(3))) void*)(l), 16, 0, 0)

// ---- pre-pass 1: K fp32 -> bf16, layout unchanged [bh][skv][d] ----
__global__ __launch_bounds__(256)
void cvt_k_kernel(const float* __restrict__ src, bf16* __restrict__ dst) {
    const size_t i = ((size_t)blockIdx.x * 256 + threadIdx.x) * 8;
    float4 a = *(const float4*)(src + i);
    float4 b = *(const float4*)(src + i + 4);
    bf16x8 f;
    f[0]=(bf16)a.x; f[1]=(bf16)a.y; f[2]=(bf16)a.z; f[3]=(bf16)a.w;
    f[4]=(bf16)b.x; f[5]=(bf16)b.y; f[6]=(bf16)b.z; f[7]=(bf16)b.w;
    *(bf16x8*)(dst + i) = f;
}

// ---- pre-pass 2: V fp32 [bh][skv][d] -> bf16 transposed [bh][d][skv] ----
__global__ __launch_bounds__(256)
void tr_v_kernel(const float* __restrict__ src, bf16* __restrict__ dst) {
    __shared__ float Tl[64][65];
    const int bh  = blockIdx.y;
    const int kv0 = (int)(blockIdx.x >> 1) * 64;
    const int d0  = (int)(blockIdx.x & 1) * 64;
    const int t   = threadIdx.x;
    const float* sp = src + (size_t)bh * SQ * DH;
#pragma unroll
    for (int i = 0; i < 4; ++i) {
        const int row = i * 16 + (t >> 4);
        const int c4  = (t & 15) * 4;
        *(float4*)&Tl[row][c4] = *(const float4*)(sp + (size_t)(kv0 + row) * DH + d0 + c4);
    }
    __syncthreads();
    bf16* dp = dst + (size_t)bh * DH * SKV;
#pragma unroll
    for (int i = 0; i < 4; ++i) {
        const int d  = i * 16 + (t >> 4);
        const int k4 = (t & 15) * 4;
        bf16x4 o;
        o[0]=(bf16)Tl[k4+0][d]; o[1]=(bf16)Tl[k4+1][d];
        o[2]=(bf16)Tl[k4+2][d]; o[3]=(bf16)Tl[k4+3][d];
        *(bf16x4*)(dp + (size_t)(d0 + d) * SKV + kv0 + k4) = o;
    }
}

// ---- main attention kernel: r0's verified 16-row-wave structure, with the
//      kv range of each q-tile SPLIT BY PARITY across two blocks (balance:
//      durations 1..16 instead of 2..32; 1024 blocks backfill 512 slots).
//      Partial (m, l, unnormalized O) merged cross-block via ticket +
//      release/acquire protocol (device scope). Hot loop identical to r0. ----
__global__ __launch_bounds__(512, 2)
void attn_fwd_kernel(const float* __restrict__ Qg, const bf16* __restrict__ Kb,
                     const bf16* __restrict__ Vb, const float* __restrict__ Bg,
                     float* __restrict__ Og, float* __restrict__ Sg,
                     float* __restrict__ Mws, float* __restrict__ Lws,
                     int* __restrict__ tickets, int* __restrict__ ready)
{
    __shared__ __attribute__((aligned(16))) bf16 Kl[2][KVB * DH];   // 2 x 16 KiB
    __shared__ __attribute__((aligned(16))) bf16 Vt[2][DH * KVB];   // 2 x 16 KiB
    __shared__ int s_tk;

    const int tid = threadIdx.x;
    const int w   = tid >> 6;
    const int ln  = tid & 63;
    const int l4  = ln >> 4;
    const int lm  = ln & 15;

    const int bh = blockIdx.x;
    const int h  = bh & (NH - 1);
    const int yy = (int)blockIdx.y;                // 0..31, heavy-first dispatch
    const int qt  = 15 - (yy >> 1);
    const int par = yy & 1;                        // kv-tile parity this block owns
    const int q0 = qt * QB;
    const int qw = q0 + w * 16;
    const int qr = qw + lm;                        // this lane's q row

    const float slope = exp2f(-0.5f * (float)(h + 1));
    const bf16* kbase = Kb + (size_t)bh * SKV * DH;
    const bf16* vbase = Vb + (size_t)bh * DH * SKV;
    const float* bprow = Bg + (size_t)qr * SKV + 8 * l4;

    // staging source offsets (verbatim r0). K: LDS slot-row rl holds GLOBAL kv
    // row sigma(rl); sigma makes swapped-QK's P land in PV's B-fragment.
    int ksrc[2], vsrc[2];
#pragma unroll
    for (int i = 0; i < 2; ++i) {
        const int seg = w * 2 + i;                 // 0..15
        const int rl  = seg * 4 + (ln >> 4);       // 0..63
        const int sig = ((rl >> 5) & 1) * 32 + ((rl >> 2) & 3) * 8 + ((rl >> 4) & 1) * 4 + (rl & 3);
        ksrc[i] = sig * DH + (((ln & 15) ^ (rl & 7)) << 3);
        const int d = seg * 8 + (ln >> 3);         // 0..127
        vsrc[i] = d * SKV + (((ln & 7) ^ (d & 7)) << 3);
    }

    auto stage = [&](int kv0n, int buf) {
#pragma unroll
        for (int i = 0; i < 2; ++i)
            GLD_LDS(kbase + (size_t)kv0n * DH + ksrc[i], &Kl[buf][(w * 2 + i) * 4 * DH]);
#pragma unroll
        for (int i = 0; i < 2; ++i)
            GLD_LDS(vbase + (size_t)kv0n + vsrc[i], &Vt[buf][(w * 2 + i) * 8 * KVB]);
    };

    // ---- Q fragments (pre-scaled, bf16) ----
    bf16x8 qf[4];
    {
        const float* qrow = Qg + (size_t)bh * SQ * DH + (size_t)qr * DH;
#pragma unroll
        for (int c = 0; c < 4; ++c) {
            const float* qp = qrow + c * 32 + l4 * 8;
            float4 a = *(const float4*)qp;
            float4 b = *(const float4*)(qp + 4);
            bf16x8 f;
            f[0]=(bf16)(a.x*SM_SCALE); f[1]=(bf16)(a.y*SM_SCALE);
            f[2]=(bf16)(a.z*SM_SCALE); f[3]=(bf16)(a.w*SM_SCALE);
            f[4]=(bf16)(b.x*SM_SCALE); f[5]=(bf16)(b.y*SM_SCALE);
            f[6]=(bf16)(b.z*SM_SCALE); f[7]=(bf16)(b.w*SM_SCALE);
            qf[c] = f;
        }
    }

    bf16x8 ones;
#pragma unroll
    for (int i = 0; i < 8; ++i) ones[i] = (bf16)1.0f;

    f32x4 acc[8];   // O^T: acc[dt][r] = O[q=qr][d = dt*16 + l4*4 + r]
#pragma unroll
    for (int dt = 0; dt < 8; ++dt) acc[dt] = (f32x4){0.f, 0.f, 0.f, 0.f};
    f32x4 accl = (f32x4){0.f, 0.f, 0.f, 0.f};   // running denominator (replicated)
    float mrow = -INFINITY;

    const int niter = qt + 1;                      // tiles par, par+2, ...

    stage(par * KVB, 0);
    f32x4 bvf[2][2];
#pragma unroll
    for (int a2 = 0; a2 < 2; ++a2)
#pragma unroll
        for (int b2 = 0; b2 < 2; ++b2)
            bvf[a2][b2] = *(const f32x4*)(bprow + par * KVB + a2 * 32 + b2 * 4);
    __syncthreads();
    int cur = 0;

    for (int t = 0; t < niter; ++t) {
        const int kv0 = (par + 2 * t) * KVB;
        if (t + 1 < niter) stage(kv0 + 2 * KVB, cur ^ 1);

        // wave-uniform liveness: 64-aligned tiles + 16-aligned rows guarantee
        // a live tile has kv0 <= qw, so every row sees >=1 visible kv (no NaN).
        const bool live = (kv0 <= qw + 15);
        if (live) {
            // ---- S^T = K (Q*scale)^T : mfma(A=K_sub, B=Q) ----
            f32x4 s[4];
#pragma unroll
            for (int m = 0; m < 4; ++m) s[m] = (f32x4){0.f, 0.f, 0.f, 0.f};
            __builtin_amdgcn_s_setprio(1);
#pragma unroll
            for (int c = 0; c < 4; ++c) {
#pragma unroll
                for (int m = 0; m < 4; ++m) {
                    bf16x8 kb = *(const bf16x8*)&Kl[cur][(m * 16 + lm) * DH +
                                    ((((c << 2) + l4) ^ (lm & 7)) << 3)];
                    s[m] = __builtin_amdgcn_mfma_f32_16x16x32_bf16(kb, qf[c], s[m], 0, 0, 0);
                }
            }
            __builtin_amdgcn_s_setprio(0);

            const int dqi = qr - kv0 - 8 * l4;   // visible iff koff <= dqi
            const float base = slope * (float)(-dqi);
            float p[4][4];
            const bool needMask = (kv0 + KVB - 1 > qw);
            if (needMask) {
#pragma unroll
                for (int m = 0; m < 4; ++m) {
                    const int a2 = m >> 1, b2 = m & 1;
#pragma unroll
                    for (int r = 0; r < 4; ++r) {
                        const int koff = a2 * 32 + b2 * 4 + r;
                        float x = s[m][r] + bvf[a2][b2][r] + fmaf(slope, (float)koff, base);
                        p[m][r] = (koff > dqi) ? -INFINITY : x;
                    }
                }
            } else {
#pragma unroll
                for (int m = 0; m < 4; ++m) {
                    const int a2 = m >> 1, b2 = m & 1;
#pragma unroll
                    for (int r = 0; r < 4; ++r) {
                        const int koff = a2 * 32 + b2 * 4 + r;
                        p[m][r] = s[m][r] + bvf[a2][b2][r] + fmaf(slope, (float)koff, base);
                    }
                }
            }

            float mxm[4];
#pragma unroll
            for (int m = 0; m < 4; ++m)
                mxm[m] = fmaxf(fmaxf(p[m][0], p[m][1]), fmaxf(p[m][2], p[m][3]));
            float mx = fmaxf(fmaxf(mxm[0], mxm[1]), fmaxf(mxm[2], mxm[3]));
            mx = fmaxf(mx, __shfl_xor(mx, 16));
            mx = fmaxf(mx, __shfl_xor(mx, 32));

            if (__any(mx > mrow + DEFER_THR)) {
                const float mn = fmaxf(mrow, mx);
                const float al = exp2f((mrow - mn) * LOG2E);
                mrow = mn;
#pragma unroll
                for (int dt = 0; dt < 8; ++dt) {
                    f32x4 a = acc[dt];
                    a[0] *= al; a[1] *= al; a[2] *= al; a[3] *= al;
                    acc[dt] = a;
                }
                accl[0] *= al; accl[1] *= al; accl[2] *= al; accl[3] *= al;
            }

#pragma unroll
            for (int m = 0; m < 4; ++m)
#pragma unroll
                for (int r = 0; r < 4; ++r)
                    p[m][r] = exp2f((p[m][r] - mrow) * LOG2E);

            // bias prefetch for this parity's next tile (hidden under PV)
            if (t + 1 < niter) {
#pragma unroll
                for (int a2 = 0; a2 < 2; ++a2)
#pragma unroll
                    for (int b2 = 0; b2 < 2; ++b2)
                        bvf[a2][b2] = *(const f32x4*)(bprow + (kv0 + 2 * KVB) + a2 * 32 + b2 * 4);
            }

            // ---- PV: O^T += V^T P^T; denom via ones-MFMA ----
            __builtin_amdgcn_s_setprio(1);
#pragma unroll
            for (int c = 0; c < 2; ++c) {
                bf16x8 pb;
                pb[0]=(bf16)p[2*c][0];   pb[1]=(bf16)p[2*c][1];
                pb[2]=(bf16)p[2*c][2];   pb[3]=(bf16)p[2*c][3];
                pb[4]=(bf16)p[2*c+1][0]; pb[5]=(bf16)p[2*c+1][1];
                pb[6]=(bf16)p[2*c+1][2]; pb[7]=(bf16)p[2*c+1][3];
                accl = __builtin_amdgcn_mfma_f32_16x16x32_bf16(ones, pb, accl, 0, 0, 0);
#pragma unroll
                for (int dt = 0; dt < 8; ++dt) {
                    bf16x8 vb = *(const bf16x8*)&Vt[cur][(dt * 16 + lm) * KVB +
                                    ((((c << 2) + l4) ^ (lm & 7)) << 3)];
                    acc[dt] = __builtin_amdgcn_mfma_f32_16x16x32_bf16(vb, pb, acc[dt], 0, 0, 0);
                }
            }
            __builtin_amdgcn_s_setprio(0);
        } else if (t + 1 < niter) {
            // keep the bias pipeline consistent for when this wave goes live
#pragma unroll
            for (int a2 = 0; a2 < 2; ++a2)
#pragma unroll
                for (int b2 = 0; b2 < 2; ++b2)
                    bvf[a2][b2] = *(const f32x4*)(bprow + (kv0 + 2 * KVB) + a2 * 32 + b2 * 4);
        }

        __syncthreads();  // drains staging vmcnt + buffer handoff
        cur ^= 1;
    }

    // ---- cross-block parity merge: ticket, then write-partial / merge ----
    const int slot = bh * 16 + qt;
    if (tid == 0)
        s_tk = __hip_atomic_fetch_add(&tickets[slot], 1, __ATOMIC_RELAXED,
                                      __HIP_MEMORY_SCOPE_AGENT);
    __syncthreads();
    float* orow = Og + (size_t)bh * SQ * DH + (size_t)qr * DH;
    if (s_tk == 0) {
        // first finisher: unnormalized O partial into Og, (m,l) into workspace
#pragma unroll
        for (int dt = 0; dt < 8; ++dt)
            *(f32x4*)(orow + dt * 16 + l4 * 4) = acc[dt];
        if (l4 == 0) {
            Mws[(size_t)bh * SQ + qr] = mrow;
            Lws[(size_t)bh * SQ + qr] = accl[0];
        }
        __threadfence();
        __syncthreads();
        if (tid == 0)
            __hip_atomic_store(&ready[slot], 1, __ATOMIC_RELEASE,
                               __HIP_MEMORY_SCOPE_AGENT);
    } else {
        if (tid == 0) {
            while (__hip_atomic_load(&ready[slot], __ATOMIC_ACQUIRE,
                                     __HIP_MEMORY_SCOPE_AGENT) == 0)
                __builtin_amdgcn_s_sleep(2);
        }
        __syncthreads();
        __threadfence();   // device-scope acquire for all lanes before reading partials
        const float m1 = Mws[(size_t)bh * SQ + qr];
        const float l1 = Lws[(size_t)bh * SQ + qr];
        const float m  = fmaxf(mrow, m1);
        const float a0 = exp2f((mrow - m) * LOG2E);   // 0 if this half was empty
        const float a1 = exp2f((m1 - m) * LOG2E);     // 0 if partner was empty
        const float dme = a0 * accl[0] + a1 * l1;
        const float inv = 1.0f / dme;
#pragma unroll
        for (int dt = 0; dt < 8; ++dt) {
            f32x4 o1 = *(const f32x4*)(orow + dt * 16 + l4 * 4);
            f32x4 o;
            o[0] = (a0 * acc[dt][0] + a1 * o1[0]) * inv;
            o[1] = (a0 * acc[dt][1] + a1 * o1[1]) * inv;
            o[2] = (a0 * acc[dt][2] + a1 * o1[2]) * inv;
            o[3] = (a0 * acc[dt][3] + a1 * o1[3]) * inv;
            *(f32x4*)(orow + dt * 16 + l4 * 4) = o;
        }
        if (l4 == 0)
            Sg[(size_t)bh * SQ + qr] = m + logf(dme);
    }
}

extern "C" void kernel_launch(void* const* d_in, const int* in_sizes, int n_in,
                              void* d_out, int out_size, void* d_ws, size_t ws_size,
                              hipStream_t stream) {
    const float* Q = (const float*)d_in[0];
    const float* K = (const float*)d_in[1];
    const float* V = (const float*)d_in[2];
    const float* B = (const float*)d_in[3];
    float* O     = (float*)d_out;
    float* Stats = O + (size_t)NB * NH * SQ * DH;

    const size_t nkv = (size_t)NB * NH * SKV * DH;
    bf16* Kb = (bf16*)d_ws;
    bf16* Vt = Kb + nkv;
    float* Mws = (float*)(Vt + nkv);
    float* Lws = Mws + (size_t)NB * NH * SQ;
    int* tickets = (int*)(Lws + (size_t)NB * NH * SQ);
    int* ready   = tickets + NB * NH * 16;

    (void)hipMemsetAsync(tickets, 0, 2 * NB * NH * 16 * sizeof(int), stream);
    cvt_k_kernel<<<(int)(nkv / (256 * 8)), 256, 0, stream>>>(K, Kb);
    tr_v_kernel<<<dim3(64, NB * NH), 256, 0, stream>>>(V, Vt);

    // y: qt = 15-(y>>1) (heavy-first dispatch), par = y&1
    dim3 grid(NB * NH, 32);
    attn_fwd_kernel<<<grid, 512, 0, stream>>>(Q, Kb, Vt, B, O, Stats,
                                              Mws, Lws, tickets, ready);
}